// Round 1
// baseline (626.692 us; speedup 1.0000x reference)
//
#include <hip/hip_runtime.h>
#include <math.h>

// ---------------------------------------------------------------------------
// SimpleGCN: 2-layer GCNConv + global mean pool + log_softmax
//   x[N,DIN] fp32, src/dst[E] int32, batch[N] int32 (sorted), W1[DIN,DH],
//   b1[DH], W2[DH,DOUT], b2[DOUT], out[G,DOUT] fp32
// Pipeline:
//   degi = indeg(dst); dinv = rsqrt(degi+1)
//   CSR by dst (rowptr/colidx) via scan + atomic fill
//   h1 = x @ W1
//   hrelu = relu(sum_e dinv[s]dinv[d] h1[s] + dinv[d]^2 h1[d] + b1)
//   h2 = hrelu @ W2
//   h2a = relu(same aggregation on h2 + b2)
//   out = log_softmax(segment_mean(h2a, batch))
// ---------------------------------------------------------------------------

__global__ __launch_bounds__(256) void k_count(const int* __restrict__ dst, int E,
                                               int* __restrict__ degi) {
    int e = blockIdx.x * 256 + threadIdx.x;
    if (e < E) atomicAdd(&degi[dst[e]], 1);
}

__global__ __launch_bounds__(256) void k_dinv(const int* __restrict__ degi,
                                              float* __restrict__ dinv, int N) {
    int i = blockIdx.x * 256 + threadIdx.x;
    if (i < N) dinv[i] = rsqrtf((float)degi[i] + 1.0f);
}

// ---- 2-level exclusive scan over degi -> rowptr --------------------------
__global__ __launch_bounds__(256) void k_scan1(const int* __restrict__ in,
                                               int* __restrict__ outp,  // rowptr+1
                                               int* __restrict__ bsums, int N) {
    __shared__ int sh[256];
    int t = threadIdx.x, b = blockIdx.x;
    int base = b * 1024 + t * 4;
    int v0 = (base + 0 < N) ? in[base + 0] : 0;
    int v1 = (base + 1 < N) ? in[base + 1] : 0;
    int v2 = (base + 2 < N) ? in[base + 2] : 0;
    int v3 = (base + 3 < N) ? in[base + 3] : 0;
    int l0 = v0, l1 = l0 + v1, l2 = l1 + v2, l3 = l2 + v3;
    sh[t] = l3;
    __syncthreads();
    int run = l3;
    for (int off = 1; off < 256; off <<= 1) {
        int y = (t >= off) ? sh[t - off] : 0;
        __syncthreads();
        run += y;
        sh[t] = run;
        __syncthreads();
    }
    int excl = run - l3;
    if (base + 0 < N) outp[base + 0] = excl + l0;
    if (base + 1 < N) outp[base + 1] = excl + l1;
    if (base + 2 < N) outp[base + 2] = excl + l2;
    if (base + 3 < N) outp[base + 3] = excl + l3;
    if (t == 255) bsums[b] = run;
}

__global__ __launch_bounds__(256) void k_scan2(const int* __restrict__ bsums,
                                               int* __restrict__ boffs, int nb) {
    __shared__ int sh[256];
    int t = threadIdx.x;
    int v = (t < nb) ? bsums[t] : 0;
    sh[t] = v;
    __syncthreads();
    int run = v;
    for (int off = 1; off < 256; off <<= 1) {
        int y = (t >= off) ? sh[t - off] : 0;
        __syncthreads();
        run += y;
        sh[t] = run;
        __syncthreads();
    }
    boffs[t] = run - v;  // exclusive
}

__global__ __launch_bounds__(256) void k_scan3(int* __restrict__ rowptr,
                                               const int* __restrict__ boffs,
                                               int* __restrict__ cursor, int N) {
    int i = blockIdx.x * 256 + threadIdx.x;
    if (i == 0) { rowptr[0] = 0; cursor[0] = 0; }
    if (i < N) {
        int v = rowptr[1 + i] + boffs[i >> 10];
        rowptr[1 + i] = v;
        if (i + 1 < N) cursor[i + 1] = v;
    }
}

__global__ __launch_bounds__(256) void k_fill(const int* __restrict__ src,
                                              const int* __restrict__ dst, int E,
                                              int* __restrict__ cursor,
                                              int* __restrict__ colidx) {
    int e = blockIdx.x * 256 + threadIdx.x;
    if (e < E) {
        int d = dst[e];
        int p = atomicAdd(&cursor[d], 1);
        colidx[p] = src[e];
    }
}

// ---- generic fp32 tiled GEMM: C[M,N] = A[M,K] @ B[K,N] -------------------
// 256 threads; BM*BN == 256*TM*TN; BM*BK == 1024; K % BK == 0; N % 4 == 0.
template <int BM, int BN, int BK, int TM, int TN>
__global__ __launch_bounds__(256) void k_gemm(const float* __restrict__ A,
                                              const float* __restrict__ B,
                                              float* __restrict__ C, int M, int N,
                                              int K) {
    __shared__ float As[BK][BM + 4];
    __shared__ float Bs[BK][BN];
    const int tid = threadIdx.x;
    const int m0 = blockIdx.x * BM;
    const int n0 = blockIdx.y * BN;
    constexpr int CT = BN / TN;
    const int tc = tid % CT, tr = tid / CT;
    const int ar = tid / (BK / 4);
    const int ak = (tid % (BK / 4)) * 4;
    float acc[TM][TN] = {};
    for (int k0 = 0; k0 < K; k0 += BK) {
        {  // stage A (transposed into LDS)
            float4 v = {0.f, 0.f, 0.f, 0.f};
            int gr = m0 + ar;
            if (gr < M) v = *(const float4*)&A[(size_t)gr * K + k0 + ak];
            As[ak + 0][ar] = v.x;
            As[ak + 1][ar] = v.y;
            As[ak + 2][ar] = v.z;
            As[ak + 3][ar] = v.w;
        }
        {  // stage B
            constexpr int LB = (BK * BN) / (256 * 4);
#pragma unroll
            for (int i = 0; i < LB; i++) {
                int idx = tid + i * 256;
                int bk = idx / (BN / 4);
                int bc = (idx % (BN / 4)) * 4;
                float4 v = {0.f, 0.f, 0.f, 0.f};
                int gc = n0 + bc;
                if (gc < N) v = *(const float4*)&B[(size_t)(k0 + bk) * N + gc];
                *(float4*)&Bs[bk][bc] = v;
            }
        }
        __syncthreads();
#pragma unroll
        for (int kk = 0; kk < BK; ++kk) {
            float a[TM], b[TN];
#pragma unroll
            for (int i = 0; i < TM; i++) a[i] = As[kk][tr * TM + i];
#pragma unroll
            for (int j = 0; j < TN; j++) b[j] = Bs[kk][tc * TN + j];
#pragma unroll
            for (int i = 0; i < TM; i++)
#pragma unroll
                for (int j = 0; j < TN; j++) acc[i][j] += a[i] * b[j];
        }
        __syncthreads();
    }
#pragma unroll
    for (int i = 0; i < TM; i++) {
        int gr = m0 + tr * TM + i;
        if (gr >= M) continue;
#pragma unroll
        for (int j = 0; j < TN; j += 4) {
            int gc = n0 + tc * TN + j;
            if (gc < N)
                *(float4*)&C[(size_t)gr * N + gc] =
                    make_float4(acc[i][j], acc[i][j + 1], acc[i][j + 2], acc[i][j + 3]);
        }
    }
}

// ---- layer-1 aggregation: DH=128, one wave per node, float2 per lane -----
__global__ __launch_bounds__(256) void k_agg1(const float* __restrict__ h1,
                                              const int* __restrict__ rowptr,
                                              const int* __restrict__ colidx,
                                              const float* __restrict__ dinv,
                                              const float* __restrict__ b1,
                                              float* __restrict__ out, int N) {
    int wid = (blockIdx.x * 256 + threadIdx.x) >> 6;
    int lane = threadIdx.x & 63;
    if (wid >= N) return;
    float dn = dinv[wid];
    int beg = rowptr[wid], end = rowptr[wid + 1];
    const float2* h1v = (const float2*)h1;
    float2 acc = {0.f, 0.f};
    for (int e = beg; e < end; ++e) {
        int s = colidx[e];
        float w = dn * dinv[s];
        float2 v = h1v[(size_t)s * 64 + lane];
        acc.x += w * v.x;
        acc.y += w * v.y;
    }
    float2 sv = h1v[(size_t)wid * 64 + lane];
    float w0 = dn * dn;
    acc.x += w0 * sv.x;
    acc.y += w0 * sv.y;
    float2 bb = ((const float2*)b1)[lane];
    acc.x = fmaxf(acc.x + bb.x, 0.f);
    acc.y = fmaxf(acc.y + bb.y, 0.f);
    ((float2*)out)[(size_t)wid * 64 + lane] = acc;
}

// ---- layer-2 aggregation: DOUT=40, one wave per node, lanes<40 -----------
__global__ __launch_bounds__(256) void k_agg2(const float* __restrict__ h2,
                                              const int* __restrict__ rowptr,
                                              const int* __restrict__ colidx,
                                              const float* __restrict__ dinv,
                                              const float* __restrict__ b2,
                                              float* __restrict__ out, int N,
                                              int DOUT) {
    int wid = (blockIdx.x * 256 + threadIdx.x) >> 6;
    int lane = threadIdx.x & 63;
    if (wid >= N || lane >= DOUT) return;
    float dn = dinv[wid];
    int beg = rowptr[wid], end = rowptr[wid + 1];
    float acc = 0.f;
    for (int e = beg; e < end; ++e) {
        int s = colidx[e];
        acc += dn * dinv[s] * h2[(size_t)s * DOUT + lane];
    }
    acc += dn * dn * h2[(size_t)wid * DOUT + lane];
    acc = fmaxf(acc + b2[lane], 0.f);
    out[(size_t)wid * DOUT + lane] = acc;
}

// ---- segment mean pool (batch sorted) + log_softmax ----------------------
__global__ __launch_bounds__(256) void k_pool(const float* __restrict__ h2a,
                                              const int* __restrict__ batch, int N,
                                              int DOUT, float* __restrict__ out) {
    int g = blockIdx.x;
    int t = threadIdx.x;
    int lo = 0, hi = N;
    while (lo < hi) {
        int mid = (lo + hi) >> 1;
        if (batch[mid] < g) lo = mid + 1; else hi = mid;
    }
    int start = lo;
    hi = N;
    while (lo < hi) {
        int mid = (lo + hi) >> 1;
        if (batch[mid] <= g) lo = mid + 1; else hi = mid;
    }
    int end = lo;
    int cnt = end - start;
    int c = t & 63, rr = t >> 6;
    float acc = 0.f;
    if (c < DOUT) {
        for (int i = start + rr; i < end; i += 4) acc += h2a[(size_t)i * DOUT + c];
    }
    __shared__ float sm[4][64];
    sm[rr][c] = acc;
    __syncthreads();
    if (t < 64) {
        float v = (c < DOUT)
                      ? (sm[0][c] + sm[1][c] + sm[2][c] + sm[3][c]) / fmaxf((float)cnt, 1.f)
                      : -1e30f;
        float m = v;
#pragma unroll
        for (int o = 32; o; o >>= 1) m = fmaxf(m, __shfl_xor(m, o));
        float ex = (c < DOUT) ? expf(v - m) : 0.f;
        float s = ex;
#pragma unroll
        for (int o = 32; o; o >>= 1) s += __shfl_xor(s, o);
        if (c < DOUT) out[g * DOUT + c] = (v - m) - logf(s);
    }
}

extern "C" void kernel_launch(void* const* d_in, const int* in_sizes, int n_in,
                              void* d_out, int out_size, void* d_ws, size_t ws_size,
                              hipStream_t stream) {
    const float* x = (const float*)d_in[0];
    const int* src = (const int*)d_in[1];
    const int* dst = (const int*)d_in[2];
    const int* batch = (const int*)d_in[3];
    const float* W1 = (const float*)d_in[4];
    const float* b1 = (const float*)d_in[5];
    const float* W2 = (const float*)d_in[6];
    const float* b2 = (const float*)d_in[7];
    float* out = (float*)d_out;

    const int N = in_sizes[3];
    const int E = in_sizes[1];
    const int DIN = in_sizes[0] / N;
    const int DH = in_sizes[5];
    const int DOUT = in_sizes[7];
    const int G = out_size / DOUT;

    char* ws = (char*)d_ws;
    size_t off = 0;
    auto alloc = [&](size_t bytes) -> char* {
        char* p = ws + off;
        off += (bytes + 255) & ~(size_t)255;
        return p;
    };
    float* h1 = (float*)alloc((size_t)N * DH * 4);  // later reused for h2/h2a
    float* hrelu = (float*)alloc((size_t)N * DH * 4);
    int* colidx = (int*)alloc((size_t)E * 4);
    int* degi = (int*)alloc((size_t)N * 4);
    int* rowptr = (int*)alloc((size_t)(N + 1) * 4);
    int* cursor = (int*)alloc((size_t)N * 4);
    float* dinv = (float*)alloc((size_t)N * 4);
    int* bsums = (int*)alloc(256 * 4);
    int* boffs = (int*)alloc(256 * 4);
    float* h2 = h1;                          // N*DOUT
    float* h2a = h1 + (size_t)N * DOUT;      // N*DOUT

    hipMemsetAsync(degi, 0, (size_t)N * 4, stream);

    const int TB = 256;
    k_count<<<(E + TB - 1) / TB, TB, 0, stream>>>(dst, E, degi);
    k_dinv<<<(N + TB - 1) / TB, TB, 0, stream>>>(degi, dinv, N);
    int nb = (N + 1023) / 1024;
    k_scan1<<<nb, TB, 0, stream>>>(degi, rowptr + 1, bsums, N);
    k_scan2<<<1, TB, 0, stream>>>(bsums, boffs, nb);
    k_scan3<<<(N + TB - 1) / TB, TB, 0, stream>>>(rowptr, boffs, cursor, N);
    k_fill<<<(E + TB - 1) / TB, TB, 0, stream>>>(src, dst, E, cursor, colidx);

    // h1 = x @ W1
    dim3 g1((N + 63) / 64, (DH + 127) / 128);
    k_gemm<64, 128, 16, 4, 8><<<g1, TB, 0, stream>>>(x, W1, h1, N, DH, DIN);
    // hrelu = relu(aggregate(h1) + b1)
    k_agg1<<<(N + 3) / 4, TB, 0, stream>>>(h1, rowptr, colidx, dinv, b1, hrelu, N);
    // h2 = hrelu @ W2
    dim3 g2((N + 63) / 64, (DOUT + 63) / 64);
    k_gemm<64, 64, 16, 4, 4><<<g2, TB, 0, stream>>>(hrelu, W2, h2, N, DOUT, DH);
    // h2a = relu(aggregate(h2) + b2)
    k_agg2<<<(N + 3) / 4, TB, 0, stream>>>(h2, rowptr, colidx, dinv, b2, h2a, N, DOUT);
    // pooled mean + log_softmax
    k_pool<<<G, TB, 0, stream>>>(h2a, batch, N, DOUT, out);
}

// Round 2
// 369.916 us; speedup vs baseline: 1.6941x; 1.6941x over previous
//
#include <hip/hip_runtime.h>
#include <math.h>

// ---------------------------------------------------------------------------
// SimpleGCN: 2-layer GCNConv + global mean pool + log_softmax
// Round 2: bf16 feature storage + MFMA GEMMs + coef-precompute + unrolled
// gather aggregation.
// ---------------------------------------------------------------------------

typedef __attribute__((ext_vector_type(4))) float f32x4;
typedef __attribute__((ext_vector_type(8))) short bf16x8;

static __device__ __forceinline__ ushort f2bf(float f) {
    union { float f; uint u; } v{f};
    uint r = (v.u + 0x7FFF + ((v.u >> 16) & 1)) >> 16;
    return (ushort)r;
}
static __device__ __forceinline__ float bflo(uint v) {
    union { uint u; float f; } o{v << 16};
    return o.f;
}
static __device__ __forceinline__ float bfhi(uint v) {
    union { uint u; float f; } o{v & 0xffff0000u};
    return o.f;
}
static __device__ __forceinline__ float bf2f(ushort h) {
    union { uint u; float f; } o{(uint)h << 16};
    return o.f;
}

// ---- degree / dinv -------------------------------------------------------
__global__ __launch_bounds__(256) void k_count(const int* __restrict__ dst, int E,
                                               int* __restrict__ degi) {
    int e = blockIdx.x * 256 + threadIdx.x;
    if (e < E) atomicAdd(&degi[dst[e]], 1);
}

__global__ __launch_bounds__(256) void k_dinv(const int* __restrict__ degi,
                                              float* __restrict__ dinv, int N) {
    int i = blockIdx.x * 256 + threadIdx.x;
    if (i < N) dinv[i] = rsqrtf((float)degi[i] + 1.0f);
}

// ---- 2-level exclusive scan over degi -> rowptr --------------------------
__global__ __launch_bounds__(256) void k_scan1(const int* __restrict__ in,
                                               int* __restrict__ outp,  // rowptr+1
                                               int* __restrict__ bsums, int N) {
    __shared__ int sh[256];
    int t = threadIdx.x, b = blockIdx.x;
    int base = b * 1024 + t * 4;
    int v0 = (base + 0 < N) ? in[base + 0] : 0;
    int v1 = (base + 1 < N) ? in[base + 1] : 0;
    int v2 = (base + 2 < N) ? in[base + 2] : 0;
    int v3 = (base + 3 < N) ? in[base + 3] : 0;
    int l0 = v0, l1 = l0 + v1, l2 = l1 + v2, l3 = l2 + v3;
    sh[t] = l3;
    __syncthreads();
    int run = l3;
    for (int off = 1; off < 256; off <<= 1) {
        int y = (t >= off) ? sh[t - off] : 0;
        __syncthreads();
        run += y;
        sh[t] = run;
        __syncthreads();
    }
    int excl = run - l3;
    if (base + 0 < N) outp[base + 0] = excl + l0;
    if (base + 1 < N) outp[base + 1] = excl + l1;
    if (base + 2 < N) outp[base + 2] = excl + l2;
    if (base + 3 < N) outp[base + 3] = excl + l3;
    if (t == 255) bsums[b] = run;
}

__global__ __launch_bounds__(256) void k_scan2(const int* __restrict__ bsums,
                                               int* __restrict__ boffs, int nb) {
    __shared__ int sh[256];
    int t = threadIdx.x;
    int v = (t < nb) ? bsums[t] : 0;
    sh[t] = v;
    __syncthreads();
    int run = v;
    for (int off = 1; off < 256; off <<= 1) {
        int y = (t >= off) ? sh[t - off] : 0;
        __syncthreads();
        run += y;
        sh[t] = run;
        __syncthreads();
    }
    boffs[t] = run - v;  // exclusive
}

__global__ __launch_bounds__(256) void k_scan3(int* __restrict__ rowptr,
                                               const int* __restrict__ boffs,
                                               int* __restrict__ cursor, int N) {
    int i = blockIdx.x * 256 + threadIdx.x;
    if (i == 0) { rowptr[0] = 0; cursor[0] = 0; }
    if (i < N) {
        int v = rowptr[1 + i] + boffs[i >> 10];
        rowptr[1 + i] = v;
        if (i + 1 < N) cursor[i + 1] = v;
    }
}

__global__ __launch_bounds__(256) void k_fill(const int* __restrict__ src,
                                              const int* __restrict__ dst,
                                              const float* __restrict__ dinv, int E,
                                              int* __restrict__ cursor,
                                              int* __restrict__ colidx,
                                              float* __restrict__ coef) {
    int e = blockIdx.x * 256 + threadIdx.x;
    if (e < E) {
        int d = dst[e], s = src[e];
        int p = atomicAdd(&cursor[d], 1);
        colidx[p] = s;
        coef[p] = dinv[s] * dinv[d];
    }
}

// ---- fp32 -> bf16 cast (x) -----------------------------------------------
__global__ __launch_bounds__(256) void k_cast(const float* __restrict__ x,
                                              ushort* __restrict__ xb, long n4) {
    long i = (long)blockIdx.x * 256 + threadIdx.x;
    if (i < n4) {
        float4 v = ((const float4*)x)[i];
        ushort4 o;
        o.x = f2bf(v.x); o.y = f2bf(v.y); o.z = f2bf(v.z); o.w = f2bf(v.w);
        *(ushort4*)&xb[i * 4] = o;
    }
}

// ---- weight prep: W1[128,128]->w1t[128][128] bf16 (T), W2[128,40]->w2t[48][128]
__global__ __launch_bounds__(256) void k_prep_w(const float* __restrict__ W1,
                                                const float* __restrict__ W2,
                                                ushort* __restrict__ w1t,
                                                ushort* __restrict__ w2t) {
    int i = blockIdx.x * 256 + threadIdx.x;
    if (i < 128 * 128) {
        int n = i >> 7, k = i & 127;
        w1t[i] = f2bf(W1[k * 128 + n]);
    } else if (i < 128 * 128 + 48 * 128) {
        int j = i - 128 * 128;
        int n = j >> 7, k = j & 127;
        w2t[j] = (n < 40) ? f2bf(W2[k * 40 + n]) : (ushort)0;
    }
}

// ---- bf16 MFMA GEMM: C[M,NCOLS] = A[M,128] @ BT[NF*16,128]^T -------------
// 256 threads = 4 waves; each block does 64 rows, full N; K = 128 (one pass).
template <int NF>
__global__ __launch_bounds__(256) void k_gemm_bf16(const ushort* __restrict__ A,
                                                   const ushort* __restrict__ BT,
                                                   ushort* __restrict__ C, int M,
                                                   int NCOLS) {
    __shared__ ushort As[64][136];
    __shared__ ushort Bs[NF * 16][136];
    const int tid = threadIdx.x;
    const int m0 = blockIdx.x * 64;
#pragma unroll
    for (int i = 0; i < 4; i++) {  // stage A: 64 rows x 16 chunks of 16B
        int chunk = tid + i * 256;
        int r = chunk >> 4, c = chunk & 15;
        float4 v = {0.f, 0.f, 0.f, 0.f};
        if (m0 + r < M) v = *(const float4*)&A[((size_t)(m0 + r)) * 128 + c * 8];
        *(float4*)&As[r][c * 8] = v;
    }
#pragma unroll
    for (int i = 0; i < NF; i++) {  // stage B: NF*16 rows x 16 chunks
        int chunk = tid + i * 256;
        int r = chunk >> 4, c = chunk & 15;
        *(float4*)&Bs[r][c * 8] = *(const float4*)&BT[(size_t)r * 128 + c * 8];
    }
    __syncthreads();
    const int wave = tid >> 6, lane = tid & 63;
    const int arow = wave * 16 + (lane & 15);
    const int kgrp = (lane >> 4) * 8;
    f32x4 acc[NF];
#pragma unroll
    for (int i = 0; i < NF; i++) acc[i] = (f32x4){0.f, 0.f, 0.f, 0.f};
#pragma unroll
    for (int kk = 0; kk < 4; kk++) {
        bf16x8 a = *(const bf16x8*)&As[arow][kk * 32 + kgrp];
#pragma unroll
        for (int nf = 0; nf < NF; nf++) {
            bf16x8 b = *(const bf16x8*)&Bs[nf * 16 + (lane & 15)][kk * 32 + kgrp];
            acc[nf] = __builtin_amdgcn_mfma_f32_16x16x32_bf16(a, b, acc[nf], 0, 0, 0);
        }
    }
    const int orow = m0 + wave * 16 + (lane >> 4) * 4;
#pragma unroll
    for (int nf = 0; nf < NF; nf++) {
        int col = nf * 16 + (lane & 15);
        if (col >= NCOLS) continue;
#pragma unroll
        for (int j = 0; j < 4; j++) {
            int r = orow + j;
            if (r < M) C[(size_t)r * NCOLS + col] = f2bf(acc[nf][j]);
        }
    }
}

// ---- layer-1 aggregation: bf16 gather, unroll 4, one wave/node -----------
__global__ __launch_bounds__(256) void k_agg1(const ushort* __restrict__ h1b,
                                              const int* __restrict__ rowptr,
                                              const int* __restrict__ colidx,
                                              const float* __restrict__ coef,
                                              const float* __restrict__ dinv,
                                              const float* __restrict__ b1,
                                              ushort* __restrict__ outb, int N) {
    int wid = (blockIdx.x * 256 + threadIdx.x) >> 6;
    int lane = threadIdx.x & 63;
    if (wid >= N) return;
    const uint* h1u = (const uint*)h1b;  // 2 bf16 per lane
    int beg = rowptr[wid], end = rowptr[wid + 1];
    float ax = 0.f, ay = 0.f;
    int e = beg;
    for (; e + 4 <= end; e += 4) {
        int s0 = colidx[e + 0], s1 = colidx[e + 1];
        int s2 = colidx[e + 2], s3 = colidx[e + 3];
        float w0 = coef[e + 0], w1 = coef[e + 1];
        float w2 = coef[e + 2], w3 = coef[e + 3];
        uint v0 = h1u[(size_t)s0 * 64 + lane];
        uint v1 = h1u[(size_t)s1 * 64 + lane];
        uint v2 = h1u[(size_t)s2 * 64 + lane];
        uint v3 = h1u[(size_t)s3 * 64 + lane];
        ax += w0 * bflo(v0) + w1 * bflo(v1) + w2 * bflo(v2) + w3 * bflo(v3);
        ay += w0 * bfhi(v0) + w1 * bfhi(v1) + w2 * bfhi(v2) + w3 * bfhi(v3);
    }
    for (; e < end; ++e) {
        int s = colidx[e];
        float w = coef[e];
        uint v = h1u[(size_t)s * 64 + lane];
        ax += w * bflo(v);
        ay += w * bfhi(v);
    }
    float dn = dinv[wid];
    uint sv = h1u[(size_t)wid * 64 + lane];
    float ws = dn * dn;
    ax += ws * bflo(sv);
    ay += ws * bfhi(sv);
    float2 bb = *(const float2*)&b1[lane * 2];
    ax = fmaxf(ax + bb.x, 0.f);
    ay = fmaxf(ay + bb.y, 0.f);
    uint packed = ((uint)f2bf(ay) << 16) | (uint)f2bf(ax);
    ((uint*)outb)[(size_t)wid * 64 + lane] = packed;
}

// ---- layer-2 aggregation: DOUT=40 bf16 gather, unroll 4 ------------------
__global__ __launch_bounds__(256) void k_agg2(const ushort* __restrict__ h2b,
                                              const int* __restrict__ rowptr,
                                              const int* __restrict__ colidx,
                                              const float* __restrict__ coef,
                                              const float* __restrict__ dinv,
                                              const float* __restrict__ b2,
                                              float* __restrict__ h2a, int N,
                                              int DOUT) {
    int wid = (blockIdx.x * 256 + threadIdx.x) >> 6;
    int lane = threadIdx.x & 63;
    if (wid >= N || lane >= DOUT) return;
    int beg = rowptr[wid], end = rowptr[wid + 1];
    float acc = 0.f;
    int e = beg;
    for (; e + 4 <= end; e += 4) {
        int s0 = colidx[e + 0], s1 = colidx[e + 1];
        int s2 = colidx[e + 2], s3 = colidx[e + 3];
        float w0 = coef[e + 0], w1 = coef[e + 1];
        float w2 = coef[e + 2], w3 = coef[e + 3];
        float v0 = bf2f(h2b[(size_t)s0 * DOUT + lane]);
        float v1 = bf2f(h2b[(size_t)s1 * DOUT + lane]);
        float v2 = bf2f(h2b[(size_t)s2 * DOUT + lane]);
        float v3 = bf2f(h2b[(size_t)s3 * DOUT + lane]);
        acc += w0 * v0 + w1 * v1 + w2 * v2 + w3 * v3;
    }
    for (; e < end; ++e) {
        acc += coef[e] * bf2f(h2b[(size_t)colidx[e] * DOUT + lane]);
    }
    float dn = dinv[wid];
    acc += dn * dn * bf2f(h2b[(size_t)wid * DOUT + lane]);
    acc = fmaxf(acc + b2[lane], 0.f);
    h2a[(size_t)wid * DOUT + lane] = acc;
}

// ---- segment mean pool (batch sorted) + log_softmax ----------------------
__global__ __launch_bounds__(256) void k_pool(const float* __restrict__ h2a,
                                              const int* __restrict__ batch, int N,
                                              int DOUT, float* __restrict__ out) {
    int g = blockIdx.x;
    int t = threadIdx.x;
    int lo = 0, hi = N;
    while (lo < hi) {
        int mid = (lo + hi) >> 1;
        if (batch[mid] < g) lo = mid + 1; else hi = mid;
    }
    int start = lo;
    hi = N;
    while (lo < hi) {
        int mid = (lo + hi) >> 1;
        if (batch[mid] <= g) lo = mid + 1; else hi = mid;
    }
    int end = lo;
    int cnt = end - start;
    int c = t & 63, rr = t >> 6;
    float acc = 0.f;
    if (c < DOUT) {
        for (int i = start + rr; i < end; i += 4) acc += h2a[(size_t)i * DOUT + c];
    }
    __shared__ float sm[4][64];
    sm[rr][c] = acc;
    __syncthreads();
    if (t < 64) {
        float v = (c < DOUT)
                      ? (sm[0][c] + sm[1][c] + sm[2][c] + sm[3][c]) / fmaxf((float)cnt, 1.f)
                      : -1e30f;
        float m = v;
#pragma unroll
        for (int o = 32; o; o >>= 1) m = fmaxf(m, __shfl_xor(m, o));
        float ex = (c < DOUT) ? expf(v - m) : 0.f;
        float s = ex;
#pragma unroll
        for (int o = 32; o; o >>= 1) s += __shfl_xor(s, o);
        if (c < DOUT) out[g * DOUT + c] = (v - m) - logf(s);
    }
}

extern "C" void kernel_launch(void* const* d_in, const int* in_sizes, int n_in,
                              void* d_out, int out_size, void* d_ws, size_t ws_size,
                              hipStream_t stream) {
    const float* x = (const float*)d_in[0];
    const int* src = (const int*)d_in[1];
    const int* dst = (const int*)d_in[2];
    const int* batch = (const int*)d_in[3];
    const float* W1 = (const float*)d_in[4];
    const float* b1 = (const float*)d_in[5];
    const float* W2 = (const float*)d_in[6];
    const float* b2 = (const float*)d_in[7];
    float* out = (float*)d_out;

    const int N = in_sizes[3];
    const int E = in_sizes[1];
    const int DOUT = in_sizes[7];
    const int G = out_size / DOUT;

    char* ws = (char*)d_ws;
    size_t off = 0;
    auto alloc = [&](size_t bytes) -> char* {
        char* p = ws + off;
        off += (bytes + 255) & ~(size_t)255;
        return p;
    };
    ushort* xb = (ushort*)alloc((size_t)N * 128 * 2);   // also reused as hrelu
    ushort* h1b = (ushort*)alloc((size_t)N * 128 * 2);  // also reused h2b/h2a
    int* colidx = (int*)alloc((size_t)E * 4);
    float* coef = (float*)alloc((size_t)E * 4);
    int* degi = (int*)alloc((size_t)N * 4);
    int* rowptr = (int*)alloc((size_t)(N + 1) * 4);
    int* cursor = (int*)alloc((size_t)N * 4);
    float* dinv = (float*)alloc((size_t)N * 4);
    int* bsums = (int*)alloc(256 * 4);
    int* boffs = (int*)alloc(256 * 4);
    ushort* w1t = (ushort*)alloc(128 * 128 * 2);
    ushort* w2t = (ushort*)alloc(48 * 128 * 2);

    ushort* hrelu = xb;                                   // alias: xb dead after gemm1
    ushort* h2b = h1b;                                    // alias: h1b dead after agg1
    float* h2a = (float*)(h1b + (size_t)N * 48);          // within h1b region, disjoint

    hipMemsetAsync(degi, 0, (size_t)N * 4, stream);

    const int TB = 256;
    k_count<<<(E + TB - 1) / TB, TB, 0, stream>>>(dst, E, degi);
    k_dinv<<<(N + TB - 1) / TB, TB, 0, stream>>>(degi, dinv, N);
    int nb = (N + 1023) / 1024;
    k_scan1<<<nb, TB, 0, stream>>>(degi, rowptr + 1, bsums, N);
    k_scan2<<<1, TB, 0, stream>>>(bsums, boffs, nb);
    k_scan3<<<(N + TB - 1) / TB, TB, 0, stream>>>(rowptr, boffs, cursor, N);
    k_fill<<<(E + TB - 1) / TB, TB, 0, stream>>>(src, dst, dinv, E, cursor, colidx, coef);

    long n4 = (long)N * 32;  // float4 count for x
    k_cast<<<(int)((n4 + TB - 1) / TB), TB, 0, stream>>>(x, xb, n4);
    k_prep_w<<<(128 * 128 + 48 * 128 + TB - 1) / TB, TB, 0, stream>>>(W1, W2, w1t, w2t);

    // h1b = xb @ W1 (bf16 out)
    k_gemm_bf16<8><<<(N + 63) / 64, TB, 0, stream>>>(xb, w1t, h1b, N, 128);
    // hrelu = relu(agg(h1b) + b1), bf16 out (aliases xb)
    k_agg1<<<(N + 3) / 4, TB, 0, stream>>>(h1b, rowptr, colidx, coef, dinv, b1, hrelu, N);
    // h2b = hrelu @ W2 (bf16 out, aliases h1b)
    k_gemm_bf16<3><<<(N + 63) / 64, TB, 0, stream>>>(hrelu, w2t, h2b, N, DOUT);
    // h2a = relu(agg(h2b) + b2), fp32
    k_agg2<<<(N + 3) / 4, TB, 0, stream>>>(h2b, rowptr, colidx, coef, dinv, b2, h2a, N, DOUT);
    // pooled mean + log_softmax
    k_pool<<<G, TB, 0, stream>>>(h2a, batch, N, DOUT, out);
}